// Round 9
// baseline (359.737 us; speedup 1.0000x reference)
//
#include <hip/hip_runtime.h>
#include <stdint.h>

// Problem constants
#define CIN_  16
#define KS_   13
#define AS_   12
#define R_    12
#define KT    96            // kappa per step
#define NSTEP 26

typedef float  f32x4  __attribute__((ext_vector_type(4)));
typedef __bf16 bf16x4 __attribute__((ext_vector_type(4)));
typedef __bf16 bf16x8 __attribute__((ext_vector_type(8)));

__device__ static inline void gll16(const void* g, void* l) {
  __builtin_amdgcn_global_load_lds(
      (const __attribute__((address_space(1))) uint32_t*)g,
      (__attribute__((address_space(3))) uint32_t*)l, 16, 0, 0);
}

// ---------------------------------------------------------------------------
// Kernel 1: expand W into MFMA-fragment-ordered WmatF.
// Frag fid = kt*36 + ks*12 + mt  (1 KB each: 64 lanes x 16B).
// Lane l, elem e:  A[row = mt*16 + (l&15)][kappa = kt*96 + ks*32 + (l>>4)*8 + e]
// row=(d*12+r), kappa=(c*13+k)*12+a,
//   Wfull[d,c,r,k,a] = W[d,c, idx_map[ tivr[r,k]*12 + tir[r,a] ]].
// ---------------------------------------------------------------------------
__global__ void build_wmatf(const float* __restrict__ W,
                            const int* __restrict__ idx_map,
                            const int* __restrict__ tivr,   // [12][13]
                            const int* __restrict__ tir,    // [12][12]
                            __bf16* __restrict__ WmatF) {
  int gid  = blockIdx.x * blockDim.x + threadIdx.x;   // 0..59903 (= 936*64)
  int lane = gid & 63;
  int fid  = gid >> 6;              // 0..935
  int kt   = fid / 36;
  int rem  = fid - kt * 36;
  int ks   = rem / 12;
  int mt   = rem - ks * 12;

  int row = mt * 16 + (lane & 15);
  int d = row / R_;
  int r = row - d * R_;

  bf16x8 v;
#pragma unroll
  for (int e = 0; e < 8; ++e) {
    int kap = kt * KT + ks * 32 + (lane >> 4) * 8 + e;
    int c = kap / (KS_ * AS_);
    int t = kap - c * (KS_ * AS_);
    int k = t / AS_;
    int a = t - k * AS_;
    int s = idx_map[tivr[r * KS_ + k] * AS_ + tir[r * AS_ + a]];
    v[e] = (__bf16)W[(d * CIN_ + c) * 36 + s];
  }
  *(bf16x8*)(WmatF + (size_t)gid * 8) = v;
}

// ---------------------------------------------------------------------------
// Kernel 2: out(b,d,p,r) = Wmat(192 x 2496) @ X(2496 x [b,p])
// 512 WGs x 256 threads (4 waves), BN=64 -> TWO INDEPENDENT WGs PER CU
// (LDS 72 KB each, exactly 2 fit) whose barrier domains drift out of phase:
// one WG computes while the other's loads are serviced -> HBM never idles.
// Each wave owns 16 private p-columns + all 192 rows (12 MFMA tiles).
// B direct from global x (x read once); A via global_load_lds from
// fragment-ordered WmatF (L2-hot), double-buffered. vmcnt(6)+bare barrier
// per step; never vmcnt(0).
// ---------------------------------------------------------------------------
template <int STORE, int REP>
__global__ __launch_bounds__(256, 2)
void s2conv_t(const float* __restrict__ x,
              const __bf16* __restrict__ WmatF,
              float* __restrict__ out) {
  __shared__ __bf16 As[2][36 * 512];   // 2 x 36 frags x 1 KB = 72 KB

  const int tid  = threadIdx.x;
  const int lane = tid & 63;
  const int wave = tid >> 6;        // 0..3 -> 16-col group
  const int l15  = lane & 15;
  const int l4   = lane >> 4;

  const int wg = blockIdx.x;        // 0..511
  const int b  = wg >> 6;           // 0..7
  const int p0 = (wg & 63) << 6;    // 64-col tile
  const int p  = p0 + wave * 16 + l15;   // this thread's private column

  // B-load byte offsets: kappa_local = ks*32 + l4*8 + h*4 -> (ck, a);
  // 4 consecutive floats, never crosses ck (a%4==0).
  int voff[3][2];
#pragma unroll
  for (int ks = 0; ks < 3; ++ks)
#pragma unroll
    for (int h = 0; h < 2; ++h) {
      int kl = ks * 32 + l4 * 8 + h * 4;
      int ck = kl / 12, a = kl - ck * 12;
      voff[ks][h] = (ck * 49152 + p * 12 + a) * 4;
    }
  const char* xb = (const char*)(x + (size_t)b * 208 * 49152);

  f32x4 acc[12];
#pragma unroll
  for (int i = 0; i < 12; ++i) acc[i] = f32x4{0.f, 0.f, 0.f, 0.f};

  // gll frags: 36 per WG / 4 waves = 9 each, no duplicates.
  const int fr0 = wave * 9;

  auto stageA = [&](int kt, int buf) {
    const char* gk = (const char*)WmatF + (size_t)kt * 36864;
    char* lb = (char*)&As[buf][0];
#pragma unroll
    for (int f = 0; f < 9; ++f)
      gll16(gk + (fr0 + f) * 1024 + lane * 16, lb + (fr0 + f) * 1024);
  };

  auto loadB = [&](int kt, f32x4 (&bs)[3][2]) {
    const char* xk = xb + (size_t)kt * (8 * 49152 * 4);
#pragma unroll
    for (int ks = 0; ks < 3; ++ks)
#pragma unroll
      for (int h = 0; h < 2; ++h)
        bs[ks][h] = *(const f32x4*)(xk + voff[ks][h]);
  };

  auto mfma_phase = [&](int buf, f32x4 (&bs)[3][2]) {
    const char* lb = (const char*)&As[buf][0];
#pragma unroll
    for (int ks = 0; ks < 3; ++ks) {
      bf16x4 lo = __builtin_convertvector(bs[ks][0], bf16x4);
      bf16x4 hi = __builtin_convertvector(bs[ks][1], bf16x4);
      bf16x8 bfr = __builtin_shufflevector(lo, hi, 0, 1, 2, 3, 4, 5, 6, 7);
#pragma unroll
      for (int mt = 0; mt < 12; ++mt) {
        bf16x8 af = *(const bf16x8*)(lb + (ks * 12 + mt) * 1024 + lane * 16);
        acc[mt] = __builtin_amdgcn_mfma_f32_16x16x32_bf16(af, bfr, acc[mt],
                                                          0, 0, 0);
      }
    }
  };

  f32x4 bsE[3][2], bsO[3][2];

#pragma unroll 1
  for (int rep = 0; rep < REP; ++rep) {
    // ---- prologue: tile 0 --------------------------------------------------
    stageA(0, 0);
    __builtin_amdgcn_sched_barrier(0);
    loadB(0, bsE);
    __builtin_amdgcn_sched_barrier(0);
    asm volatile("s_waitcnt vmcnt(6)" ::: "memory");  // A(0) landed; B(0) flies
    __builtin_amdgcn_s_barrier();

    // ---- main loop: steps 0..23, fully unconditional -----------------------
#pragma unroll 1
    for (int j = 0; j < 24; j += 2) {
      stageA(j + 1, 1);
      __builtin_amdgcn_sched_barrier(0);
      loadB(j + 1, bsO);
      __builtin_amdgcn_sched_barrier(0);
      mfma_phase(0, bsE);
      asm volatile("s_waitcnt vmcnt(6)" ::: "memory");
      __builtin_amdgcn_s_barrier();

      stageA(j + 2, 0);
      __builtin_amdgcn_sched_barrier(0);
      loadB(j + 2, bsE);
      __builtin_amdgcn_sched_barrier(0);
      mfma_phase(1, bsO);
      asm volatile("s_waitcnt vmcnt(6)" ::: "memory");
      __builtin_amdgcn_s_barrier();
    }
    // step 24
    stageA(25, 1);
    __builtin_amdgcn_sched_barrier(0);
    loadB(25, bsO);
    __builtin_amdgcn_sched_barrier(0);
    mfma_phase(0, bsE);
    asm volatile("s_waitcnt vmcnt(6)" ::: "memory");
    __builtin_amdgcn_s_barrier();
    // step 25 (tail: no new loads)
    mfma_phase(1, bsO);
    if constexpr (REP > 1) __builtin_amdgcn_s_barrier();
  }

  if constexpr (STORE) {
    // ---- epilogue: col=l15 (=p), row = mt*16 + l4*4 + reg ------------------
#pragma unroll
    for (int mt = 0; mt < 12; ++mt) {
      int mrow0 = mt * 16 + l4 * 4;        // r0 in {0,4,8} -> same d
      int d  = mrow0 / 12;
      int r0 = mrow0 - d * 12;
      float* dst = out + (size_t)((b * 16 + d) * 4096 + p) * 12 + r0;
      *(f32x4*)dst = acc[mt];              // 16B aligned
    }
  } else {
#pragma unroll
    for (int i = 0; i < 12; ++i) asm volatile("" :: "v"(acc[i]));
  }
}

// ---------------------------------------------------------------------------
extern "C" void kernel_launch(void* const* d_in, const int* in_sizes, int n_in,
                              void* d_out, int out_size, void* d_ws, size_t ws_size,
                              hipStream_t stream) {
  const float* x       = (const float*)d_in[0];  // (8,16,13,4096,12) f32
  const float* W       = (const float*)d_in[1];  // (16,16,36) f32
  const int*   idx_map = (const int*)d_in[2];    // (156,)
  const int*   tivr    = (const int*)d_in[3];    // (12,13)
  const int*   tir     = (const int*)d_in[4];    // (12,12)
  float*       out     = (float*)d_out;          // (8,16,4096,12) f32
  __bf16*      WmatF   = (__bf16*)d_ws;          // 936 KB, fragment-ordered

  build_wmatf<<<dim3(117), dim3(512), 0, stream>>>(W, idx_map, tivr, tir, WmatF);
  s2conv_t<1, 1><<<dim3(512), dim3(256), 0, stream>>>(x, WmatF, out);   // REAL
  // instrumentation replica (no store): lands in rocprof top-5 with counters
  s2conv_t<0, 5><<<dim3(512), dim3(256), 0, stream>>>(x, WmatF, out);
}

// Round 10
// 82.204 us; speedup vs baseline: 4.3762x; 4.3762x over previous
//
#include <hip/hip_runtime.h>
#include <stdint.h>

// Problem constants
#define CIN_  16
#define KS_   13
#define AS_   12
#define R_    12
#define KT    96            // kappa per step
#define NSTEP 26

typedef float  f32x4  __attribute__((ext_vector_type(4)));
typedef __bf16 bf16x4 __attribute__((ext_vector_type(4)));
typedef __bf16 bf16x8 __attribute__((ext_vector_type(8)));

__device__ static inline void gll16(const void* g, void* l) {
  __builtin_amdgcn_global_load_lds(
      (const __attribute__((address_space(1))) uint32_t*)g,
      (__attribute__((address_space(3))) uint32_t*)l, 16, 0, 0);
}

// ---------------------------------------------------------------------------
// Kernel 1: expand W into MFMA-fragment-ordered WmatF.
// Frag fid = kt*36 + ks*12 + mt  (1 KB each: 64 lanes x 16B).
// Lane l, elem e:  A[row = mt*16 + (l&15)][kappa = kt*96 + ks*32 + (l>>4)*8 + e]
// row=(d*12+r), kappa=(c*13+k)*12+a,
//   Wfull[d,c,r,k,a] = W[d,c, idx_map[ tivr[r,k]*12 + tir[r,a] ]].
// ---------------------------------------------------------------------------
__global__ void build_wmatf(const float* __restrict__ W,
                            const int* __restrict__ idx_map,
                            const int* __restrict__ tivr,   // [12][13]
                            const int* __restrict__ tir,    // [12][12]
                            __bf16* __restrict__ WmatF) {
  int gid  = blockIdx.x * blockDim.x + threadIdx.x;   // 0..59903 (= 936*64)
  int lane = gid & 63;
  int fid  = gid >> 6;              // 0..935
  int kt   = fid / 36;
  int rem  = fid - kt * 36;
  int ks   = rem / 12;
  int mt   = rem - ks * 12;

  int row = mt * 16 + (lane & 15);
  int d = row / R_;
  int r = row - d * R_;

  bf16x8 v;
#pragma unroll
  for (int e = 0; e < 8; ++e) {
    int kap = kt * KT + ks * 32 + (lane >> 4) * 8 + e;
    int c = kap / (KS_ * AS_);
    int t = kap - c * (KS_ * AS_);
    int k = t / AS_;
    int a = t - k * AS_;
    int s = idx_map[tivr[r * KS_ + k] * AS_ + tir[r * AS_ + a]];
    v[e] = (__bf16)W[(d * CIN_ + c) * 36 + s];
  }
  *(bf16x8*)(WmatF + (size_t)gid * 8) = v;
}

// ---------------------------------------------------------------------------
// Kernel 2: out(b,d,p,r) = Wmat(192 x 2496) @ X(2496 x [b,p])
// 512 WGs x 256 threads (4 waves), BN=64 -> TWO INDEPENDENT WGs PER CU
// (LDS 72 KB each, exactly 2 fit) whose barrier domains drift out of phase:
// one WG computes while the other's loads are serviced -> HBM never idles.
// (R8 ablation evidence: this structure ~60 us/rep, VGPR=128, 0 bank
//  conflicts, vs 78 us plateau for every 1-WG/CU schedule.)
// Each wave owns 16 private p-columns + all 192 rows (12 MFMA tiles).
// B direct from global x (x read once); A via global_load_lds from
// fragment-ordered WmatF (L2-hot), double-buffered. vmcnt(6)+bare barrier
// per step; never vmcnt(0).
// ---------------------------------------------------------------------------
__global__ __launch_bounds__(256, 2)
void s2conv(const float* __restrict__ x,
            const __bf16* __restrict__ WmatF,
            float* __restrict__ out) {
  __shared__ __bf16 As[2][36 * 512];   // 2 x 36 frags x 1 KB = 72 KB

  const int tid  = threadIdx.x;
  const int lane = tid & 63;
  const int wave = tid >> 6;        // 0..3 -> 16-col group
  const int l15  = lane & 15;
  const int l4   = lane >> 4;

  const int wg = blockIdx.x;        // 0..511
  const int b  = wg >> 6;           // 0..7
  const int p0 = (wg & 63) << 6;    // 64-col tile
  const int p  = p0 + wave * 16 + l15;   // this thread's private column

  // B-load byte offsets: kappa_local = ks*32 + l4*8 + h*4 -> (ck, a);
  // 4 consecutive floats, never crosses ck (a%4==0).
  int voff[3][2];
#pragma unroll
  for (int ks = 0; ks < 3; ++ks)
#pragma unroll
    for (int h = 0; h < 2; ++h) {
      int kl = ks * 32 + l4 * 8 + h * 4;
      int ck = kl / 12, a = kl - ck * 12;
      voff[ks][h] = (ck * 49152 + p * 12 + a) * 4;
    }
  const char* xb = (const char*)(x + (size_t)b * 208 * 49152);

  f32x4 acc[12];
#pragma unroll
  for (int i = 0; i < 12; ++i) acc[i] = f32x4{0.f, 0.f, 0.f, 0.f};

  // gll frags: 36 per WG / 4 waves = 9 each, no duplicates.
  const int fr0 = wave * 9;

  auto stageA = [&](int kt, int buf) {
    const char* gk = (const char*)WmatF + (size_t)kt * 36864;
    char* lb = (char*)&As[buf][0];
#pragma unroll
    for (int f = 0; f < 9; ++f)
      gll16(gk + (fr0 + f) * 1024 + lane * 16, lb + (fr0 + f) * 1024);
  };

  auto loadB = [&](int kt, f32x4 (&bs)[3][2]) {
    const char* xk = xb + (size_t)kt * (8 * 49152 * 4);
#pragma unroll
    for (int ks = 0; ks < 3; ++ks)
#pragma unroll
      for (int h = 0; h < 2; ++h)
        bs[ks][h] = *(const f32x4*)(xk + voff[ks][h]);
  };

  auto mfma_phase = [&](int buf, f32x4 (&bs)[3][2]) {
    const char* lb = (const char*)&As[buf][0];
#pragma unroll
    for (int ks = 0; ks < 3; ++ks) {
      bf16x4 lo = __builtin_convertvector(bs[ks][0], bf16x4);
      bf16x4 hi = __builtin_convertvector(bs[ks][1], bf16x4);
      bf16x8 bfr = __builtin_shufflevector(lo, hi, 0, 1, 2, 3, 4, 5, 6, 7);
#pragma unroll
      for (int mt = 0; mt < 12; ++mt) {
        bf16x8 af = *(const bf16x8*)(lb + (ks * 12 + mt) * 1024 + lane * 16);
        acc[mt] = __builtin_amdgcn_mfma_f32_16x16x32_bf16(af, bfr, acc[mt],
                                                          0, 0, 0);
      }
    }
  };

  f32x4 bsE[3][2], bsO[3][2];

  // ---- prologue: tile 0 ----------------------------------------------------
  stageA(0, 0);
  __builtin_amdgcn_sched_barrier(0);
  loadB(0, bsE);
  __builtin_amdgcn_sched_barrier(0);
  asm volatile("s_waitcnt vmcnt(6)" ::: "memory");  // A(0) landed; B(0) flies
  __builtin_amdgcn_s_barrier();

  // ---- main loop: steps 0..23, fully unconditional -------------------------
#pragma unroll 1
  for (int j = 0; j < 24; j += 2) {
    stageA(j + 1, 1);
    __builtin_amdgcn_sched_barrier(0);
    loadB(j + 1, bsO);
    __builtin_amdgcn_sched_barrier(0);
    mfma_phase(0, bsE);
    asm volatile("s_waitcnt vmcnt(6)" ::: "memory");
    __builtin_amdgcn_s_barrier();

    stageA(j + 2, 0);
    __builtin_amdgcn_sched_barrier(0);
    loadB(j + 2, bsE);
    __builtin_amdgcn_sched_barrier(0);
    mfma_phase(1, bsO);
    asm volatile("s_waitcnt vmcnt(6)" ::: "memory");
    __builtin_amdgcn_s_barrier();
  }
  // step 24
  stageA(25, 1);
  __builtin_amdgcn_sched_barrier(0);
  loadB(25, bsO);
  __builtin_amdgcn_sched_barrier(0);
  mfma_phase(0, bsE);
  asm volatile("s_waitcnt vmcnt(6)" ::: "memory");
  __builtin_amdgcn_s_barrier();
  // step 25 (tail: no new loads)
  mfma_phase(1, bsO);

  // ---- epilogue: col=l15 (=p), row = mt*16 + l4*4 + reg --------------------
#pragma unroll
  for (int mt = 0; mt < 12; ++mt) {
    int mrow0 = mt * 16 + l4 * 4;        // r0 in {0,4,8} -> same d
    int d  = mrow0 / 12;
    int r0 = mrow0 - d * 12;
    float* dst = out + (size_t)((b * 16 + d) * 4096 + p) * 12 + r0;
    *(f32x4*)dst = acc[mt];              // 16B aligned
  }
}

// ---------------------------------------------------------------------------
extern "C" void kernel_launch(void* const* d_in, const int* in_sizes, int n_in,
                              void* d_out, int out_size, void* d_ws, size_t ws_size,
                              hipStream_t stream) {
  const float* x       = (const float*)d_in[0];  // (8,16,13,4096,12) f32
  const float* W       = (const float*)d_in[1];  // (16,16,36) f32
  const int*   idx_map = (const int*)d_in[2];    // (156,)
  const int*   tivr    = (const int*)d_in[3];    // (12,13)
  const int*   tir     = (const int*)d_in[4];    // (12,12)
  float*       out     = (float*)d_out;          // (8,16,4096,12) f32
  __bf16*      WmatF   = (__bf16*)d_ws;          // 936 KB, fragment-ordered

  build_wmatf<<<dim3(117), dim3(512), 0, stream>>>(W, idx_map, tivr, tir, WmatF);
  s2conv<<<dim3(512), dim3(256), 0, stream>>>(x, WmatF, out);
}